// Round 1
// baseline (205.115 us; speedup 1.0000x reference)
//
#include <hip/hip_runtime.h>

#define L 4096
#define BLOCK 512
#define PPT (L / BLOCK)  // 8 positions per thread, strided for coalescing

__global__ __launch_bounds__(BLOCK)
void extrema1d_kernel(const float* __restrict__ x,
                      const int* __restrict__ dptr,
                      float* __restrict__ out) {
    __shared__ float s_x[L];
    __shared__ float s_key[L];           // |x| if active extremum, -1 otherwise
    __shared__ unsigned char s_win[L];   // this-round winner flags
    __shared__ unsigned char s_keep[L];  // final keep mask
    __shared__ int s_any;

    const int row = blockIdx.x;
    const int tid = threadIdx.x;
    const int d = *dptr;
    const float* __restrict__ xr = x + (size_t)row * L;

    // Stage row into LDS (coalesced: lane-consecutive global addresses).
    for (int k = 0; k < PPT; ++k) {
        int i = tid + k * BLOCK;
        s_x[i] = xr[i];
        s_keep[i] = 0;
    }
    __syncthreads();

    // Extrema mask, matching reference pad semantics exactly:
    //   dxr[i] = (i<L-1) && (x[i+1]-x[i] > 0)      (right-pad with 0 -> false)
    //   dxl[i] = (i==0)  || (x[i]-x[i-1] <= 0)     (left-pad with 0  -> true)
    //   neg[i] = (1 - sign(x)) != 0  <=>  !(x > 0)
    for (int k = 0; k < PPT; ++k) {
        int i = tid + k * BLOCK;
        float xi = s_x[i];
        bool dxr = (i < L - 1) && ((s_x[i + 1] - xi) > 0.0f);
        bool dxl = (i == 0) || ((xi - s_x[i - 1]) <= 0.0f);
        bool neg = !(xi > 0.0f);
        bool valley = dxr && dxl && neg;
        bool peak = (!dxr) && (!dxl) && (!neg);
        s_key[i] = (valley || peak) ? fabsf(xi) : -1.0f;
    }
    __syncthreads();

    // Parallel-rounds greedy NMS (exact fixed point of the sequential greedy,
    // tie-break (|x| desc, index asc) matches JAX stable argsort on -key).
    for (;;) {
        if (tid == 0) s_any = 0;
        __syncthreads();

        bool any_local = false;
        for (int k = 0; k < PPT; ++k) {
            int i = tid + k * BLOCK;
            float mykey = s_key[i];
            unsigned char win = 0;
            if (mykey >= 0.0f) {            // active extremum
                any_local = true;
                win = 1;
                int lo = i - d; if (lo < 0) lo = 0;
                int hi = i + d; if (hi > L - 1) hi = L - 1;
                for (int j = lo; j <= hi; ++j) {
                    if (j == i) continue;
                    float kj = s_key[j];
                    // j dominates i if larger, or equal with lower index
                    if (kj > mykey || (kj == mykey && j < i)) { win = 0; break; }
                }
            }
            s_win[i] = win;
        }
        if (any_local) s_any = 1;           // benign LDS race, all write 1
        __syncthreads();
        if (!s_any) break;

        // Apply winners: keep self, deactivate entire window (incl. self).
        // Two same-round winners are always > d apart, so a winner's own slot
        // is never clobbered by another winner; overlapping suppression writes
        // are identical (-1) -> benign.
        for (int k = 0; k < PPT; ++k) {
            int i = tid + k * BLOCK;
            if (s_win[i]) {
                s_keep[i] = 1;
                int lo = i - d; if (lo < 0) lo = 0;
                int hi = i + d; if (hi > L - 1) hi = L - 1;
                for (int j = lo; j <= hi; ++j) s_key[j] = -1.0f;
            }
        }
        __syncthreads();
    }

    // Emit: kept extrema pass through, everything else zero (d_out is poisoned).
    float* __restrict__ orow = out + (size_t)row * L;
    for (int k = 0; k < PPT; ++k) {
        int i = tid + k * BLOCK;
        orow[i] = s_keep[i] ? s_x[i] : 0.0f;
    }
}

extern "C" void kernel_launch(void* const* d_in, const int* in_sizes, int n_in,
                              void* d_out, int out_size, void* d_ws, size_t ws_size,
                              hipStream_t stream) {
    const float* x = (const float*)d_in[0];
    const int* dptr = (const int*)d_in[1];
    float* out = (float*)d_out;
    const int B = out_size / L;  // 128
    extrema1d_kernel<<<B, BLOCK, 0, stream>>>(x, dptr, out);
}

// Round 2
// 137.071 us; speedup vs baseline: 1.4964x; 1.4964x over previous
//
#include <hip/hip_runtime.h>

#define L 4096
#define BLOCK 512
#define PPT (L / BLOCK)   // 8 positions per thread (strided ownership in rounds)
#define DPAD 64           // zero pad each side of enc: unclamped reads for d<=64

typedef unsigned long long u64;

// enc[i] encoding: active extremum -> (bits(|x|) << 32) | (0xFFFFFFFF - i)
//   lexicographic u64 max == (larger |x|, then smaller index) — exactly JAX's
//   stable argsort(-key) tie-break. 0 = inactive/suppressed. 1 = KEPT marker
//   (cannot collide: any real active enc >= 0xFFFFF000 > 1, and a later-round
//   winner is always > d away from an earlier one, so markers are never
//   overwritten by suppression).
__global__ __launch_bounds__(BLOCK)
void extrema1d_kernel(const float* __restrict__ x,
                      const int* __restrict__ dptr,
                      float* __restrict__ out) {
    __shared__ float s_x[L];
    __shared__ u64 s_enc_raw[L + 2 * DPAD];
    __shared__ int s_any[2];

    u64* __restrict__ enc = s_enc_raw + DPAD;

    const int row = blockIdx.x;
    const int tid = threadIdx.x;
    const int d = *dptr;
    const float* __restrict__ xr = x + (size_t)row * L;

    // ---- stage input: contiguous float4 per thread (lane-coalesced 1KB/wave-instr)
    {
        const float4* __restrict__ src = (const float4*)xr;
        float4 a = src[2 * tid];
        float4 b = src[2 * tid + 1];
        float4* dst = (float4*)&s_x[8 * tid];
        dst[0] = a;
        dst[1] = b;
    }
    if (tid < 2 * DPAD)
        s_enc_raw[tid < DPAD ? tid : (L + DPAD + tid - DPAD)] = 0ULL;
    if (tid == 0) { s_any[0] = 0; s_any[1] = 0; }
    __syncthreads();

    // ---- extrema mask -> enc. Strided ownership i = tid + k*BLOCK:
    // lane-consecutive LDS addresses in all round-phase accesses (dense, no
    // bank conflicts). Reference pad semantics: dxr[L-1]=false, dxl[0]=true,
    // neg = !(x>0).
    unsigned alive = 0;  // bit k <-> position tid + k*BLOCK still active
    #pragma unroll
    for (int k = 0; k < PPT; ++k) {
        int i = tid + k * BLOCK;
        float xi = s_x[i];
        bool dxr = (i < L - 1) && ((s_x[i + 1] - xi) > 0.0f);
        bool dxl = (i == 0) || ((xi - s_x[i - 1]) <= 0.0f);
        bool neg = !(xi > 0.0f);
        bool ext = (dxr && dxl && neg) || (!dxr && !dxl && !neg);
        u64 e = 0;
        if (ext) {
            e = ((u64)__float_as_uint(fabsf(xi)) << 32) |
                (u64)(0xFFFFFFFFu - (unsigned)i);
            alive |= 1u << k;
        }
        enc[i] = e;
    }
    __syncthreads();

    // Cached blocker per owned position (register-resident, loops unrolled so
    // indices are static). -1 = unknown -> full rescan.
    int blk[PPT];
    #pragma unroll
    for (int k = 0; k < PPT; ++k) blk[k] = -1;

    int parity = 0;
    for (;;) {
        unsigned win = 0;
        #pragma unroll
        for (int k = 0; k < PPT; ++k) {
            if (!(alive & (1u << k))) continue;
            const int p = tid + k * BLOCK;
            const u64 me = enc[p];
            if (me == 0) { alive &= ~(1u << k); continue; }  // suppressed since
            const int b = blk[k];
            if (b >= 0 && enc[b] > me) continue;  // cached blocker still dominates
            // Full window rescan: independent loads, no early exit -> pipelined.
            u64 best = 0;
            int bj = -1;
            if (d == 32) {
                #pragma unroll
                for (int j = 1; j <= 32; ++j) {
                    u64 e1 = enc[p - j];
                    u64 e2 = enc[p + j];
                    if (e1 > best) { best = e1; bj = p - j; }
                    if (e2 > best) { best = e2; bj = p + j; }
                }
            } else {
                int lo = p - d; if (lo < 0) lo = 0;
                int hi = p + d; if (hi > L - 1) hi = L - 1;
                for (int j = lo; j <= hi; ++j) {
                    if (j == p) continue;
                    u64 e = enc[j];
                    if (e > best) { best = e; bj = j; }
                }
            }
            if (best > me) {
                blk[k] = bj;              // new dominator found, cache it
            } else {
                win |= 1u << k;           // window max (incl. tie-break) is me
                alive &= ~(1u << k);
            }
        }
        if (__any((int)(alive != 0)) && (tid & 63) == 0) s_any[parity] = 1;
        __syncthreads();

        // ---- apply winners: mark kept, suppress window. Same-round winners
        // are mutually > d apart, so markers are never clobbered; overlapping
        // suppression writes are identical zeros (benign).
        #pragma unroll
        for (int k = 0; k < PPT; ++k) {
            if (win & (1u << k)) {
                const int p = tid + k * BLOCK;
                int lo = p - d; if (lo < 0) lo = 0;
                int hi = p + d; if (hi > L - 1) hi = L - 1;
                for (int j = lo; j <= hi; ++j) enc[j] = 0ULL;
                enc[p] = 1ULL;            // kept marker
            }
        }
        if (tid == 0) s_any[parity ^ 1] = 0;
        __syncthreads();
        if (!s_any[parity]) break;
        parity ^= 1;
    }

    // ---- emit: kept -> x, else 0 ----
    float* __restrict__ orow = out + (size_t)row * L;
    #pragma unroll
    for (int k = 0; k < PPT; ++k) {
        int i = tid + k * BLOCK;
        orow[i] = (enc[i] == 1ULL) ? s_x[i] : 0.0f;
    }
}

extern "C" void kernel_launch(void* const* d_in, const int* in_sizes, int n_in,
                              void* d_out, int out_size, void* d_ws, size_t ws_size,
                              hipStream_t stream) {
    const float* x = (const float*)d_in[0];
    const int* dptr = (const int*)d_in[1];
    float* out = (float*)d_out;
    const int B = out_size / L;  // 128
    extrema1d_kernel<<<B, BLOCK, 0, stream>>>(x, dptr, out);
}

// Round 3
// 91.293 us; speedup vs baseline: 2.2468x; 1.5014x over previous
//
#include <hip/hip_runtime.h>

#define L 4096
#define BLOCK 512
#define LANES 64
#define NWAVE (BLOCK / LANES)   // 8 waves
#define SEG (L / NWAVE)         // 512 positions per wave (contiguous segment)
#define KSTEPS (SEG / LANES)    // 8 lane-dense 64-wide steps per sweep
#define DPAD 32                 // zero guard each side: unclamped +-32 window

typedef unsigned long long u64;
#define SENT (~0ULL)

static __device__ __forceinline__ u64 umax64(u64 a, u64 b) { return a > b ? a : b; }

// enc[i]: active extremum -> (bits(|x|)<<32) | (0xFFFFFFFF - i)  [u64 max ==
// (|x| desc, index asc) == JAX stable argsort(-key) tie-break].
// 0 = suppressed/none. SENT (all-ones) = KEPT. SENT dominates every priority,
// so any racy reader of a kept item defers — combined with enc being
// monotonically non-increasing per slot (pri -> 0, or pri -> SENT terminal),
// "win iff window-max" is correct under ANY cross-wave interleaving:
// a lane can only win when every larger-priority window-mate has a
// *committed* 0 (permanently suppressed). No barriers needed in the loop.
__global__ __launch_bounds__(BLOCK)
void extrema1d_kernel(const float* __restrict__ x,
                      const int* __restrict__ dptr,
                      float* __restrict__ out) {
    __shared__ float s_x[L];
    __shared__ u64 s_enc_raw[L + 2 * DPAD];
    u64* enc = s_enc_raw + DPAD;

    const int row = blockIdx.x;
    const int tid = threadIdx.x;
    const int lane = tid & (LANES - 1);
    const int wave = tid >> 6;
    const int wbase = wave * SEG;
    const int d = *dptr;
    const float* __restrict__ xr = x + (size_t)row * L;

    // ---- stage row (coalesced float4) + zero guard pads ----
    {
        const float4* __restrict__ src = (const float4*)xr;
        float4 a = src[2 * tid];
        float4 b = src[2 * tid + 1];
        ((float4*)&s_x[8 * tid])[0] = a;
        ((float4*)&s_x[8 * tid])[1] = b;
    }
    if (tid < 2 * DPAD)
        s_enc_raw[(tid < DPAD) ? tid : (L + DPAD + (tid - DPAD))] = 0ULL;
    __syncthreads();

    // ---- extrema mask -> enc, in the sweep's (wave,k,lane) mapping ----
    // Reference pad semantics: dxr[L-1]=false, dxl[0]=true, neg = !(x>0).
    unsigned alive = 0;  // bit k <-> position wbase + 64k + lane
    #pragma unroll
    for (int k = 0; k < KSTEPS; ++k) {
        int p = wbase + (k << 6) + lane;
        float xi = s_x[p];
        bool dxr = (p < L - 1) && ((s_x[p + 1] - xi) > 0.0f);
        bool dxl = (p == 0) || ((xi - s_x[p - 1]) <= 0.0f);
        bool neg = !(xi > 0.0f);
        bool ext = (dxr && dxl && neg) || (!dxr && !dxl && !neg);
        u64 e = 0;
        if (ext) {
            e = ((u64)__float_as_uint(fabsf(xi)) << 32) |
                (u64)(0xFFFFFFFFu - (unsigned)p);
            alive |= 1u << k;
        }
        enc[p] = e;
    }
    __syncthreads();

    // ---- barrier-free chaotic sweeps, alternating direction ----
    int dir = 0;
    while (__any((int)(alive != 0u))) {
        for (int kk = 0; kk < KSTEPS; ++kk) {
            const int k = dir ? (KSTEPS - 1 - kk) : kk;
            const bool act = (alive >> k) & 1u;
            if (!__any((int)act)) continue;          // wave-uniform skip
            const int p = wbase + (k << 6) + lane;   // lane-dense LDS addrs
            u64 me = 0;
            bool scan = false;
            if (act) {
                me = ((volatile u64*)enc)[p];        // fresh: detect own death
                if (me == 0ULL) alive &= ~(1u << k);
                else scan = true;
            }
            if (__any((int)scan)) {
                u64 best = 0;
                if (scan) {
                    if (d == 32) {                   // unclamped: pads absorb
                        #pragma unroll 8
                        for (int j = 1; j <= 32; ++j) {
                            u64 e1 = enc[p - j];
                            u64 e2 = enc[p + j];
                            best = umax64(best, umax64(e1, e2));
                        }
                    } else {
                        int lo = p - d; if (lo < 0) lo = 0;
                        int hi = p + d; if (hi > L - 1) hi = L - 1;
                        for (int j = lo; j <= hi; ++j)
                            if (j != p) best = umax64(best, enc[j]);
                    }
                }
                if (scan && best < me) {             // window-max -> keep
                    enc[p] = SENT;
                    if (d == 32) {
                        #pragma unroll 8
                        for (int j = 1; j <= 32; ++j) {
                            enc[p - j] = 0ULL;
                            enc[p + j] = 0ULL;
                        }
                    } else {
                        int lo = p - d; if (lo < 0) lo = 0;
                        int hi = p + d; if (hi > L - 1) hi = L - 1;
                        for (int j = lo; j <= hi; ++j)
                            if (j != p) enc[j] = 0ULL;
                    }
                    alive &= ~(1u << k);
                }
            }
        }
        __threadfence_block();  // bound cross-wave staleness per pass
        dir ^= 1;               // zigzag: resolve both chain orientations
    }
    __syncthreads();

    // ---- emit (strided: conflict-free LDS, coalesced global) ----
    float* __restrict__ orow = out + (size_t)row * L;
    #pragma unroll
    for (int k = 0; k < KSTEPS; ++k) {
        int i = tid + k * BLOCK;
        orow[i] = (enc[i] == SENT) ? s_x[i] : 0.0f;
    }
}

extern "C" void kernel_launch(void* const* d_in, const int* in_sizes, int n_in,
                              void* d_out, int out_size, void* d_ws, size_t ws_size,
                              hipStream_t stream) {
    const float* x = (const float*)d_in[0];
    const int* dptr = (const int*)d_in[1];
    float* out = (float*)d_out;
    const int B = out_size / L;  // 128
    extrema1d_kernel<<<B, BLOCK, 0, stream>>>(x, dptr, out);
}

// Round 4
// 86.089 us; speedup vs baseline: 2.3826x; 1.0604x over previous
//
#include <hip/hip_runtime.h>

#define L 4096
#define BLOCK 512
#define LANES 64
#define NWAVE (BLOCK / LANES)   // 8 waves, one contiguous 512-segment each
#define SEG (L / NWAVE)
#define KSTEPS (SEG / LANES)    // 8 chunks of 64 per wave
#define DPAD 64                 // zero guard: unclamped prev/next chunk reads

typedef unsigned long long u64;
#define SENT (~0ULL)

static __device__ __forceinline__ u64 umax64(u64 a, u64 b) { return a > b ? a : b; }

// One max-scan step via DPP (VALU-only, no LDS traffic). bound_ctrl=false +
// old=0 -> out-of-row lanes contribute identity 0.
template<int CTRL, int RM>
static __device__ __forceinline__ u64 dpp_step(u64 v) {
    unsigned lo = (unsigned)v, hi = (unsigned)(v >> 32);
    unsigned slo = (unsigned)__builtin_amdgcn_update_dpp(0, (int)lo, CTRL, RM, 0xf, false);
    unsigned shi = (unsigned)__builtin_amdgcn_update_dpp(0, (int)hi, CTRL, RM, 0xf, false);
    return umax64(v, ((u64)shi << 32) | (u64)slo);
}

// Inclusive 64-lane prefix-max (canonical GCN DPP scan: 4x row_shr + 2 bcast).
static __device__ __forceinline__ u64 scanmax64(u64 v) {
    v = dpp_step<0x111, 0xf>(v);  // row_shr:1
    v = dpp_step<0x112, 0xf>(v);  // row_shr:2
    v = dpp_step<0x114, 0xf>(v);  // row_shr:4
    v = dpp_step<0x118, 0xf>(v);  // row_shr:8
    v = dpp_step<0x142, 0xa>(v);  // row_bcast:15 -> rows 1,3
    v = dpp_step<0x143, 0xc>(v);  // row_bcast:31 -> rows 2,3
    return v;
}

// enc[i]: active -> (bits(|x|)<<32)|(0xFFFFFFFF-i); 0 = suppressed; SENT = kept.
// Per-slot history is pri -> {0 | SENT}, both terminal; every dominator of p
// holds a value > enc[p] from init until death => any (even stale) window-max
// estimate that covers [p-32,p+32] can never hide a live dominator => "win iff
// wm == me" is sound under arbitrary cross-wave interleaving; defers retry.
__global__ __launch_bounds__(BLOCK)
void extrema1d_kernel(const float* __restrict__ x,
                      const int* __restrict__ dptr,
                      float* __restrict__ out) {
    __shared__ float s_x[L];
    __shared__ u64 s_enc_raw[L + 2 * DPAD];
    u64* enc = s_enc_raw + DPAD;

    const int row = blockIdx.x;
    const int tid = threadIdx.x;
    const int lane = tid & (LANES - 1);
    const int wave = tid >> 6;
    const int wbase = wave * SEG;
    const int d = *dptr;
    const float* __restrict__ xr = x + (size_t)row * L;

    // ---- stage row (coalesced float4) + zero pads ----
    {
        const float4* __restrict__ src = (const float4*)xr;
        float4 a = src[2 * tid];
        float4 b = src[2 * tid + 1];
        ((float4*)&s_x[8 * tid])[0] = a;
        ((float4*)&s_x[8 * tid])[1] = b;
    }
    if (tid < 2 * DPAD)
        s_enc_raw[(tid < DPAD) ? tid : (DPAD + L + (tid - DPAD))] = 0ULL;
    __syncthreads();

    // ---- extrema mask -> enc (reference pads: dxr[L-1]=F, dxl[0]=T, neg=!(x>0))
    unsigned alive = 0;  // bit k <-> position wbase + 64k + lane
    #pragma unroll
    for (int k = 0; k < KSTEPS; ++k) {
        int p = wbase + (k << 6) + lane;
        float xi = s_x[p];
        bool dxr = (p < L - 1) && ((s_x[p + 1] - xi) > 0.0f);
        bool dxl = (p == 0) || ((xi - s_x[p - 1]) <= 0.0f);
        bool neg = !(xi > 0.0f);
        bool ext = (dxr && dxl && neg) || (!dxr && !dxl && !neg);
        u64 e = 0;
        if (ext) {
            e = ((u64)__float_as_uint(fabsf(xi)) << 32) |
                (u64)(0xFFFFFFFFu - (unsigned)p);
            alive |= 1u << k;
        }
        enc[p] = e;
    }
    __syncthreads();

    if (d == 32) {
        // ---- zigzag chaotic sweeps; O(1) window-max via 2-chunk Gil-Werman ----
        int dir = 0;
        while (__any((int)(alive != 0u))) {
            for (int kk = 0; kk < KSTEPS; ++kk) {
                const int k = dir ? (KSTEPS - 1 - kk) : kk;
                if (!__any((int)((alive >> k) & 1u))) continue;
                const int q = wbase + (k << 6);
                const int p = q + lane;
                for (int rep = 0; rep < 3; ++rep) {
                    const bool act = (alive >> k) & 1u;
                    // fresh chunk reads (volatile: cross-wave updates)
                    u64 ePr = ((volatile u64*)enc)[q - 64 + 63 - lane]; // prev, reversed
                    u64 eC  = ((volatile u64*)enc)[p];                  // mine
                    u64 eCr = ((volatile u64*)enc)[q + 63 - lane];      // mine, reversed
                    u64 eN  = ((volatile u64*)enc)[q + 64 + lane];      // next
                    u64 me = eC;
                    if (act && me == 0ULL) alive &= ~(1u << k);
                    bool scan = act && (me != 0ULL);
                    if (!__any((int)scan)) break;
                    u64 S_P = scanmax64(ePr);  // lane l: max(encPrev[63-l..63])
                    u64 Pc  = scanmax64(eC);   // lane l: max(encC[0..l])
                    u64 S_C = scanmax64(eCr);  // lane l: max(encC[63-l..63])
                    u64 Pn  = scanmax64(eN);   // lane l: max(encN[0..l])
                    // window [p-32,p+32]: o<32 -> max(sufP[o+32], prefC[o+32])
                    //                     o>=32 -> max(sufC[o-32], prefN[o-32])
                    // fetch lanes: idxP=o^32 (pref arrays), 63-idxP (rev-scan arrays)
                    u64 sendS = (lane < 32) ? S_P : S_C;
                    u64 sendP = (lane < 32) ? Pn : Pc;
                    int idxP = lane ^ 32;
                    u64 wm = umax64((u64)__shfl(sendS, 63 - idxP),
                                    (u64)__shfl(sendP, idxP));
                    bool winlane = scan && (wm == me);
                    if (!__any((int)winlane)) break;
                    if (winlane) {
                        enc[p] = SENT;
                        #pragma unroll
                        for (int j = 1; j <= 32; ++j) {
                            enc[p - j] = 0ULL;
                            enc[p + j] = 0ULL;
                        }
                        alive &= ~(1u << k);
                    }
                    // rep: re-decide same chunk so intra-chunk chains resolve now
                }
            }
            __threadfence_block();
            dir ^= 1;
        }
    } else {
        // ---- generic-d fallback (R3 structure, clamped scans) ----
        int dir = 0;
        while (__any((int)(alive != 0u))) {
            for (int kk = 0; kk < KSTEPS; ++kk) {
                const int k = dir ? (KSTEPS - 1 - kk) : kk;
                const bool act = (alive >> k) & 1u;
                if (!__any((int)act)) continue;
                const int p = wbase + (k << 6) + lane;
                u64 me = 0;
                bool scan = false;
                if (act) {
                    me = ((volatile u64*)enc)[p];
                    if (me == 0ULL) alive &= ~(1u << k);
                    else scan = true;
                }
                if (__any((int)scan)) {
                    u64 best = 0;
                    int lo = p - d; if (lo < 0) lo = 0;
                    int hi = p + d; if (hi > L - 1) hi = L - 1;
                    if (scan)
                        for (int j = lo; j <= hi; ++j)
                            if (j != p) best = umax64(best, enc[j]);
                    if (scan && best < me) {
                        enc[p] = SENT;
                        for (int j = lo; j <= hi; ++j)
                            if (j != p) enc[j] = 0ULL;
                        alive &= ~(1u << k);
                    }
                }
            }
            __threadfence_block();
            dir ^= 1;
        }
    }
    __syncthreads();

    // ---- emit ----
    float* __restrict__ orow = out + (size_t)row * L;
    #pragma unroll
    for (int k = 0; k < KSTEPS; ++k) {
        int i = tid + k * BLOCK;
        orow[i] = (enc[i] == SENT) ? s_x[i] : 0.0f;
    }
}

extern "C" void kernel_launch(void* const* d_in, const int* in_sizes, int n_in,
                              void* d_out, int out_size, void* d_ws, size_t ws_size,
                              hipStream_t stream) {
    const float* x = (const float*)d_in[0];
    const int* dptr = (const int*)d_in[1];
    float* out = (float*)d_out;
    const int B = out_size / L;  // 128
    extrema1d_kernel<<<B, BLOCK, 0, stream>>>(x, dptr, out);
}